// Round 18
// baseline (126.317 us; speedup 1.0000x reference)
//
#include <hip/hip_runtime.h>
#include <hip/hip_bf16.h>
#include <stdint.h>

#define N_NODES 50000
#define N_EDGES 800000
#define D 128
#define NLAYER 3
#define NGROUP (N_NODES / 16)     // 3125 groups of 16 nodes
#define CAPG 384                   // max edges/group incl 16 self (Poisson(256)+7s)
#define GSTRIDE 384                // segment stride == CAPG
#define MAXCH 12                   // CAPG/32

#define NBKT2 196                  // coarse buckets of 256 nodes (dst >> 8)
#define BCAP 4608                  // bucket capacity (Poisson(4082) + ~8 sigma)
#define EPB_A 1024
#define PA_BLOCKS ((N_EDGES + EPB_A - 1) / EPB_A)   // 782

#define NW_PREP (NLAYER * 2 * 4 * 8 * 64)           // 12288 wconv threads
#define NH_PREP (N_NODES * D / 8)                   // 800000 h2f8 threads

typedef __attribute__((ext_vector_type(8))) short bf16x8;
typedef __attribute__((ext_vector_type(4))) float f32x4;
typedef __attribute__((ext_vector_type(2))) float f32x2;

__device__ __forceinline__ short f2bf(float f) {
    union { float f; uint32_t u; } v; v.f = f;
    uint32_t u = v.u;
    uint32_t r = u + 0x7fffu + ((u >> 16) & 1u);   // round-to-nearest-even
    return (short)(r >> 16);
}

__device__ __forceinline__ unsigned char f2fp8(float f) {
    return (unsigned char)(__builtin_amdgcn_cvt_pk_fp8_f32(f, f, 0u, false) & 0xFF);
}
__device__ __forceinline__ float fp8_to_f32(unsigned char b) {
    f32x2 p = __builtin_amdgcn_cvt_pk_f32_fp8((uint32_t)b, false);
    return p.x;
}

// ---------------------------------------------------------------------------
// Fused setup: wconv (bf16 B-frag-swizzled weights) + h2f8 (fp8 table) +
// bcur zeroing — all independent, one launch.
// ---------------------------------------------------------------------------
__global__ __launch_bounds__(256) void prep(const float* __restrict__ W1,
                                            const float* __restrict__ W2,
                                            short* __restrict__ Wswz,
                                            const float* __restrict__ h,
                                            unsigned char* __restrict__ hf8,
                                            int* __restrict__ bcur) {
    int t = blockIdx.x * blockDim.x + threadIdx.x;
    if (t < NBKT2) bcur[t] = 0;
    if (t < NW_PREP) {
        int lane = t & 63;
        int nt   = (t >> 6) & 7;
        int ks   = (t >> 9) & 3;
        int mat  = (t >> 11) & 1;
        int l    = t >> 12;
        const float* W = (mat == 0 ? W1 : W2) + (size_t)l * D * D;
        int n = nt * 16 + (lane & 15);
        short* outp = Wswz + (size_t)t * 8;
#pragma unroll
        for (int j = 0; j < 8; ++j) {
            int k = ks * 32 + (lane >> 4) * 8 + j;
            outp[j] = f2bf(W[k * D + n]);
        }
    } else {
        int th = t - NW_PREP;
        if (th < NH_PREP) {
            f32x4 a = ((const f32x4*)h)[2 * th];
            f32x4 b = ((const f32x4*)h)[2 * th + 1];
            uint32_t lo = 0, hi = 0;
            lo = __builtin_amdgcn_cvt_pk_fp8_f32(a.x, a.y, lo, false);
            lo = __builtin_amdgcn_cvt_pk_fp8_f32(a.z, a.w, lo, true);
            hi = __builtin_amdgcn_cvt_pk_fp8_f32(b.x, b.y, hi, false);
            hi = __builtin_amdgcn_cvt_pk_fp8_f32(b.z, b.w, hi, true);
            ((uint2*)hf8)[th] = make_uint2(lo, hi);
        }
    }
}

// ---------------------------------------------------------------------------
// Pass A: bin edges into 196 fixed-base coarse buckets (256 nodes each).
// EPB=1024 -> 782 blocks (~3/CU); LDS histogram is only 196 entries so the
// per-block sweep cost stays negligible.
// ---------------------------------------------------------------------------
__global__ __launch_bounds__(256) void packA(const int* __restrict__ src,
                                             const int* __restrict__ dst,
                                             int* __restrict__ bcur,
                                             int* __restrict__ epack) {
    __shared__ int hcnt[NBKT2];
    __shared__ int hbase[NBKT2];
    if (threadIdx.x < NBKT2) hcnt[threadIdx.x] = 0;
    __syncthreads();
    int base = blockIdx.x * EPB_A;
    int end = base + EPB_A; if (end > N_EDGES) end = N_EDGES;
    for (int e = base + threadIdx.x; e < end; e += 256)
        atomicAdd(&hcnt[dst[e] >> 8], 1);
    __syncthreads();
    if (threadIdx.x < NBKT2) {
        int c = hcnt[threadIdx.x];
        hbase[threadIdx.x] = c ? atomicAdd(&bcur[threadIdx.x], c) : 0;
        hcnt[threadIdx.x] = 0;               // reuse as local rank cursor
    }
    __syncthreads();
    for (int e = base + threadIdx.x; e < end; e += 256) {
        int s = src[e], d = dst[e];
        int b = d >> 8;
        int r = atomicAdd(&hcnt[b], 1);
        int slot = hbase[b] + r;
        if (slot < BCAP)
            epack[(size_t)b * BCAP + slot] = (s << 8) | (d & 255);
    }
}

// ---------------------------------------------------------------------------
// Pass B: TWO blocks per bucket (each owns 8 of the 16 groups) -> 392 blocks.
// Scans the whole bucket range, ranks/stores only its half. Segments are
// PRE-SEEDED with 16 self-edges (slots 0..15, value (node<<8)|k).
// ---------------------------------------------------------------------------
__global__ __launch_bounds__(256) void segB(const int* __restrict__ epack,
                                            const int* __restrict__ bcur,
                                            int* __restrict__ esd,
                                            int* __restrict__ gcnt) {
    __shared__ int image[8 * GSTRIDE];       // 12 KB
    __shared__ int cur[8];
    const int blk  = blockIdx.x;
    const int b    = blk >> 1;               // bucket
    const int half = blk & 1;                // group-half 0..1
    int n = bcur[b]; if (n > BCAP) n = BCAP;
    const int* ep = epack + (size_t)b * BCAP;
    const int gbase = b * 16 + half * 8;     // first global group of this half
    int nG = NGROUP - gbase; if (nG > 8) nG = 8; if (nG < 0) nG = 0;
    if (nG == 0) return;
    const int n0b = gbase * 16;              // first node of this half

    for (int i = threadIdx.x; i < 8 * GSTRIDE; i += 256) {
        int gi = i / GSTRIDE, sl = i - gi * GSTRIDE;
        image[i] = (sl < 16) ? (((n0b + gi * 16 + sl) << 8) | sl) : 0x80;
    }
    if (threadIdx.x < 8) cur[threadIdx.x] = 16;      // self-edges pre-seeded
    __syncthreads();
    for (int i = threadIdx.x; i < n; i += 256) {
        int e = ep[i];
        int g = (e >> 4) & 15;
        if ((g >> 3) == half) {
            int gl = g & 7;
            int r = atomicAdd(&cur[gl], 1);
            if (r < CAPG) image[gl * GSTRIDE + r] = e & ~0xF0;  // strip group bits
        }
    }
    __syncthreads();
    if (threadIdx.x < nG) {
        int c = cur[threadIdx.x];
        gcnt[gbase + threadIdx.x] = (c > CAPG) ? CAPG : c;
    }
    for (int i = threadIdx.x; i < nG * GSTRIDE; i += 256)
        esd[(size_t)gbase * GSTRIDE + i] = image[i];
}

// ---------------------------------------------------------------------------
// Fused GIN layer, fp8 end-to-end, barrier-free private-wave pipeline
// (identical to the passing R16/R17 kernel).
// ---------------------------------------------------------------------------
__global__ __launch_bounds__(256) void gin_layer(const unsigned char* __restrict__ hf8,
                                                 const int* __restrict__ gcnt,
                                                 const int* __restrict__ esd,
                                                 const short* __restrict__ Wl,
                                                 const float* __restrict__ b1,
                                                 const float* __restrict__ b2,
                                                 const float* __restrict__ eps, int l,
                                                 float* __restrict__ outf,
                                                 unsigned char* __restrict__ outf8,
                                                 int last) {
    __shared__ union {
        unsigned char stg[2][4096];                   // 2 x 4KB fp8 staging
        struct { short zl[2048]; short hl[2048]; } t; // MLP tiles (overlay)
    } sm;
    __shared__ int ilist[MAXCH * 32];                 // 1.5 KB
    __shared__ __align__(8) unsigned char dmask[MAXCH * 32];

    const int lane = threadIdx.x & 63;
    const int wid  = threadIdx.x >> 6;
    const int g    = blockIdx.x;
    const int n0   = g * 16;
    const int m    = lane & 15;          // A-row (node) / C-col
    const int kh   = lane >> 4;          // k-quarter

    const int lo  = g * GSTRIDE;
    int cnt = gcnt[g]; if (cnt > CAPG) cnt = CAPG;
    const int nch = (cnt + 31) >> 5;                 // 1..12 (>=16 self edges)

    // staging-lane geometry (proven in R14)
    const int eL   = ((lane >> 3) & 3) * 8 + (lane & 7);  // edge within chunk
    const int tcol = (wid * 2 + (lane >> 5)) * 16;        // col byte offset

    const uint32_t stg_base =
        (uint32_t)(uintptr_t)(__attribute__((address_space(3))) unsigned char*)&sm.stg[0][0];

    f32x4 acc[2];
    acc[0] = (f32x4)(0.0f); acc[1] = (f32x4)(0.0f);

    const int* ep = esd + lo;

    // ---- prologue: cooperative ilist + dmask build (natural order) ----
    for (int i = threadIdx.x; i < MAXCH * 32; i += 256) {
        int v = ep[i];
        ilist[i] = v;
        dmask[i] = (unsigned char)(v & 0xFF);
    }
    __syncthreads();    // also drains the coop global loads

#define STAGE(c, buf) do { \
        int _i = ilist[(c) * 32 + eL]; \
        __builtin_amdgcn_global_load_lds( \
            (const __attribute__((address_space(1))) void*)(hf8 + (((uint32_t)(_i & ~0xFF)) >> 1) + tcol), \
            (__attribute__((address_space(3))) void*)(&sm.stg[(buf)][wid * 1024]), 16, 0, 0); \
    } while (0)

    if (nch > 0) STAGE(0, 0);
    if (nch > 1) STAGE(1, 1);

    // ---- barrier-free chunk loop (per-wave private pipeline, depth-2) ----
#pragma unroll
    for (int c = 0; c < MAXCH; ++c) {
        if (c >= nch) break;
        if (c + 1 < nch) asm volatile("s_waitcnt vmcnt(1)" ::: "memory");
        else             asm volatile("s_waitcnt vmcnt(0)" ::: "memory");
        __builtin_amdgcn_sched_barrier(0);

        // one tr_b8 per col-tile: full K=32 fp8 B-fragment each
        uint32_t breg = stg_base + (uint32_t)((c & 1) * 4096 + wid * 1024) + lane * 8;
        uint64_t tb0, tb1;
        asm volatile("ds_read_b64_tr_b8 %0, %1"            : "=v"(tb0) : "v"(breg));
        asm volatile("ds_read_b64_tr_b8 %0, %1 offset:512" : "=v"(tb1) : "v"(breg));
        uint2 dm = *(const uint2*)&dmask[c * 32 + kh * 8];
        asm volatile("s_waitcnt lgkmcnt(0)" ::: "memory");
        __builtin_amdgcn_sched_barrier(0);

        // reuse buf[c&1] for chunk c+2 (our own tr reads just retired)
        if (c + 2 < nch) STAGE(c + 2, c & 1);

        // fp8 A-mask via exact per-byte zero-detect: byte k = (dst_k==m)?1.0:0
        uint32_t ms = (uint32_t)m * 0x01010101u;
        uint32_t x0 = dm.x ^ ms, x1 = dm.y ^ ms;
        uint32_t z0 = ~(((x0 & 0x7F7F7F7Fu) + 0x7F7F7F7Fu) | x0) & 0x80808080u;
        uint32_t z1 = ~(((x1 & 0x7F7F7F7Fu) + 0x7F7F7F7Fu) | x1) & 0x80808080u;
        uint32_t alo = (z0 >> 7) * 0x38u;
        uint32_t ahi = (z1 >> 7) * 0x38u;
        long amask = (long)(((uint64_t)ahi << 32) | (uint64_t)alo);

        acc[0] = __builtin_amdgcn_mfma_f32_16x16x32_fp8_fp8(amask, (long)tb0, acc[0], 0, 0, 0);
        acc[1] = __builtin_amdgcn_mfma_f32_16x16x32_fp8_fp8(amask, (long)tb1, acc[1], 0, 0, 0);
    }

    // ---- eps fallback: acc += eps * h[self] (uniform branch; eps=0 here) ----
    {
        const float epsl = eps[l];
        if (epsl != 0.0f) {
#pragma unroll
            for (int t = 0; t < 2; ++t) {
                int col = (wid * 2 + t) * 16 + m;
#pragma unroll
                for (int r = 0; r < 4; ++r) {
                    int row = n0 + kh * 4 + r;
                    acc[t][r] += epsl * fp8_to_f32(hf8[(size_t)row * D + col]);
                }
            }
        }
    }

    __syncthreads();   // drains everything; safe to overlay zl/hl on stg

    // ---- z (C layout) -> zl LDS, granule-swizzled for MLP A-frags ----
#pragma unroll
    for (int t = 0; t < 2; ++t) {
        int col = (wid * 2 + t) * 16 + m;
        int gi = col >> 3, ci = col & 7;
#pragma unroll
        for (int r = 0; r < 4; ++r) {
            int row = kh * 4 + r;
            sm.t.zl[row * 128 + ((gi ^ (row & 7)) << 3) + ci] = f2bf(acc[t][r]);
        }
    }
    __syncthreads();

    // ---- MLP stage 1: hid = relu(z @ W1 + b1) ----
    f32x4 acc1[2];
    acc1[0] = (f32x4)(0.0f); acc1[1] = (f32x4)(0.0f);
#pragma unroll
    for (int ks = 0; ks < 4; ++ks) {
        int gidx = ks * 4 + kh;
        bf16x8 af = *(const bf16x8*)&sm.t.zl[m * 128 + ((gidx ^ (m & 7)) * 8)];
#pragma unroll
        for (int t = 0; t < 2; ++t) {
            int nt = wid * 2 + t;
            bf16x8 bf = *(const bf16x8*)(Wl + ((size_t)(ks * 8 + nt) * 64 + lane) * 8);
            acc1[t] = __builtin_amdgcn_mfma_f32_16x16x32_bf16(af, bf, acc1[t], 0, 0, 0);
        }
    }
#pragma unroll
    for (int t = 0; t < 2; ++t) {
        int col = (wid * 2 + t) * 16 + m;
        float bias = b1[col];
#pragma unroll
        for (int r = 0; r < 4; ++r) {
            int hrow = kh * 4 + r;
            float v = fmaxf(acc1[t][r] + bias, 0.0f);
            sm.t.hl[hrow * 128 + (col ^ ((hrow & 7) << 3))] = f2bf(v);
        }
    }
    __syncthreads();

    // ---- MLP stage 2: out = hid @ W2 + b2 ----
    f32x4 acc2[2];
    acc2[0] = (f32x4)(0.0f); acc2[1] = (f32x4)(0.0f);
    const short* W2p = Wl + 4 * 8 * 64 * 8;
#pragma unroll
    for (int ks = 0; ks < 4; ++ks) {
        int c0 = ks * 32 + kh * 8;
        bf16x8 af = *(const bf16x8*)&sm.t.hl[m * 128 + (c0 ^ ((m & 7) << 3))];
#pragma unroll
        for (int t = 0; t < 2; ++t) {
            int nt = wid * 2 + t;
            bf16x8 bf = *(const bf16x8*)(W2p + ((size_t)(ks * 8 + nt) * 64 + lane) * 8);
            acc2[t] = __builtin_amdgcn_mfma_f32_16x16x32_bf16(af, bf, acc2[t], 0, 0, 0);
        }
    }
#pragma unroll
    for (int t = 0; t < 2; ++t) {
        int col = (wid * 2 + t) * 16 + m;
        float bias = b2[col];
#pragma unroll
        for (int r = 0; r < 4; ++r) {
            int orow = n0 + kh * 4 + r;        // exact grid, always < N_NODES
            float v = acc2[t][r] + bias;
            if (last) outf[(size_t)orow * D + col] = v;
            else      outf8[(size_t)orow * D + col] = f2fp8(v);
        }
    }
#undef STAGE
}

extern "C" void kernel_launch(void* const* d_in, const int* in_sizes, int n_in,
                              void* d_out, int out_size, void* d_ws, size_t ws_size,
                              hipStream_t stream) {
    const float* h   = (const float*)d_in[0];
    const int*   src = (const int*)d_in[1];
    const int*   dst = (const int*)d_in[2];
    const float* W1  = (const float*)d_in[3];
    const float* b1  = (const float*)d_in[4];
    const float* W2  = (const float*)d_in[5];
    const float* b2  = (const float*)d_in[6];
    const float* eps = (const float*)d_in[7];
    float* out = (float*)d_out;

    char* ws = (char*)d_ws;
    const size_t MB = 1024 * 1024;
    unsigned char* hf8A = (unsigned char*)ws;             // 6.4 MB
    unsigned char* hf8B = (unsigned char*)(ws + 7 * MB);  // 6.4 MB
    short* Wswz = (short*)(ws + 14 * MB);                 // 196 KB
    int*   gcnt = (int*)(ws + 14 * MB + 512 * 1024);      // 12.5 KB
    int*   bcur = (int*)(ws + 14 * MB + 768 * 1024);      // 0.8 KB
    int*   esd  = (int*)(ws + 15 * MB);                   // 4.8 MB
    int*   epack= (int*)(ws + 20 * MB);                   // 3.6 MB

    const int prep_blocks = (NW_PREP + NH_PREP + 255) / 256;   // 3174
    prep<<<prep_blocks, 256, 0, stream>>>(W1, W2, Wswz, h, hf8A, bcur);
    packA<<<PA_BLOCKS, 256, 0, stream>>>(src, dst, bcur, epack);
    segB<<<NBKT2 * 2, 256, 0, stream>>>(epack, bcur, esd, gcnt);

    const unsigned char* f8in[3] = {hf8A, hf8B, hf8A};
    unsigned char* houtf8[3] = {hf8B, hf8A, nullptr};

    for (int l = 0; l < NLAYER; ++l) {
        gin_layer<<<NGROUP, 256, 0, stream>>>(f8in[l], gcnt, esd,
                                              Wswz + (size_t)l * 2 * 16384,
                                              b1 + (size_t)l * D, b2 + (size_t)l * D,
                                              eps, l, out, houtf8[l],
                                              l == NLAYER - 1 ? 1 : 0);
    }
}

// Round 19
// 119.023 us; speedup vs baseline: 1.0613x; 1.0613x over previous
//
#include <hip/hip_runtime.h>
#include <hip/hip_bf16.h>
#include <stdint.h>

#define N_NODES 50000
#define N_EDGES 800000
#define D 128
#define NLAYER 3
#define NGROUP (N_NODES / 16)     // 3125 groups of 16 nodes
#define CAPG 384                   // max edges/group incl 16 self (Poisson(256)+7s)
#define GSTRIDE 384                // segment stride == CAPG
#define MAXCH 12                   // CAPG/32

#define NBKT2 196                  // coarse buckets of 256 nodes (dst >> 8)
#define BCAP 4608                  // bucket capacity (Poisson(4082) + ~8 sigma)
#define EPB_A 2048
#define PA_BLOCKS ((N_EDGES + EPB_A - 1) / EPB_A)   // 391

#define NW_PREP (NLAYER * 2 * 4 * 8 * 64)           // 12288 wconv threads
#define NH_PREP (N_NODES * D / 8)                   // 800000 h2f8 threads

typedef __attribute__((ext_vector_type(8))) short bf16x8;
typedef __attribute__((ext_vector_type(4))) float f32x4;
typedef __attribute__((ext_vector_type(2))) float f32x2;

__device__ __forceinline__ short f2bf(float f) {
    union { float f; uint32_t u; } v; v.f = f;
    uint32_t u = v.u;
    uint32_t r = u + 0x7fffu + ((u >> 16) & 1u);   // round-to-nearest-even
    return (short)(r >> 16);
}

__device__ __forceinline__ unsigned char f2fp8(float f) {
    return (unsigned char)(__builtin_amdgcn_cvt_pk_fp8_f32(f, f, 0u, false) & 0xFF);
}
__device__ __forceinline__ float fp8_to_f32(unsigned char b) {
    f32x2 p = __builtin_amdgcn_cvt_pk_f32_fp8((uint32_t)b, false);
    return p.x;
}

// ---------------------------------------------------------------------------
// Fused setup: wconv (bf16 B-frag-swizzled weights) + h2f8 (fp8 table) +
// bcur zeroing — all independent, one launch.
// ---------------------------------------------------------------------------
__global__ __launch_bounds__(256) void prep(const float* __restrict__ W1,
                                            const float* __restrict__ W2,
                                            short* __restrict__ Wswz,
                                            const float* __restrict__ h,
                                            unsigned char* __restrict__ hf8,
                                            int* __restrict__ bcur) {
    int t = blockIdx.x * blockDim.x + threadIdx.x;
    if (t < NBKT2) bcur[t] = 0;
    if (t < NW_PREP) {
        int lane = t & 63;
        int nt   = (t >> 6) & 7;
        int ks   = (t >> 9) & 3;
        int mat  = (t >> 11) & 1;
        int l    = t >> 12;
        const float* W = (mat == 0 ? W1 : W2) + (size_t)l * D * D;
        int n = nt * 16 + (lane & 15);
        short* outp = Wswz + (size_t)t * 8;
#pragma unroll
        for (int j = 0; j < 8; ++j) {
            int k = ks * 32 + (lane >> 4) * 8 + j;
            outp[j] = f2bf(W[k * D + n]);
        }
    } else {
        int th = t - NW_PREP;
        if (th < NH_PREP) {
            f32x4 a = ((const f32x4*)h)[2 * th];
            f32x4 b = ((const f32x4*)h)[2 * th + 1];
            uint32_t lo = 0, hi = 0;
            lo = __builtin_amdgcn_cvt_pk_fp8_f32(a.x, a.y, lo, false);
            lo = __builtin_amdgcn_cvt_pk_fp8_f32(a.z, a.w, lo, true);
            hi = __builtin_amdgcn_cvt_pk_fp8_f32(b.x, b.y, hi, false);
            hi = __builtin_amdgcn_cvt_pk_fp8_f32(b.z, b.w, hi, true);
            ((uint2*)hf8)[th] = make_uint2(lo, hi);
        }
    }
}

// ---------------------------------------------------------------------------
// Pass A: bin edges into 196 fixed-base coarse buckets (256 nodes each).
// ---------------------------------------------------------------------------
__global__ __launch_bounds__(256) void packA(const int* __restrict__ src,
                                             const int* __restrict__ dst,
                                             int* __restrict__ bcur,
                                             int* __restrict__ epack) {
    __shared__ int hcnt[NBKT2];
    __shared__ int hbase[NBKT2];
    if (threadIdx.x < NBKT2) hcnt[threadIdx.x] = 0;
    __syncthreads();
    int base = blockIdx.x * EPB_A;
    int end = base + EPB_A; if (end > N_EDGES) end = N_EDGES;
    for (int e = base + threadIdx.x; e < end; e += 256)
        atomicAdd(&hcnt[dst[e] >> 8], 1);
    __syncthreads();
    if (threadIdx.x < NBKT2) {
        int c = hcnt[threadIdx.x];
        hbase[threadIdx.x] = c ? atomicAdd(&bcur[threadIdx.x], c) : 0;
        hcnt[threadIdx.x] = 0;               // reuse as local rank cursor
    }
    __syncthreads();
    for (int e = base + threadIdx.x; e < end; e += 256) {
        int s = src[e], d = dst[e];
        int b = d >> 8;
        int r = atomicAdd(&hcnt[b], 1);
        int slot = hbase[b] + r;
        if (slot < BCAP)
            epack[(size_t)b * BCAP + slot] = (s << 8) | (d & 255);
    }
}

// ---------------------------------------------------------------------------
// Pass B: one block per bucket -> per-group fixed segments, coalesced out.
// Each group's segment is PRE-SEEDED with its 16 self-edges (slots 0..15,
// value (node<<8)|k) so the GIN self term rides the generic mask-MFMA path.
// ---------------------------------------------------------------------------
__global__ __launch_bounds__(256) void segB(const int* __restrict__ epack,
                                            const int* __restrict__ bcur,
                                            int* __restrict__ esd,
                                            int* __restrict__ gcnt) {
    __shared__ int image[16 * GSTRIDE];      // 24 KB
    __shared__ int cur[16];
    const int b = blockIdx.x;
    int n = bcur[b]; if (n > BCAP) n = BCAP;
    const int* ep = epack + (size_t)b * BCAP;
    const int nG = (NGROUP - b * 16 < 16) ? (NGROUP - b * 16) : 16;
    const int n0b = b * 256;

    for (int i = threadIdx.x; i < 16 * GSTRIDE; i += 256) {
        int gi = i / GSTRIDE, sl = i - gi * GSTRIDE;
        image[i] = (sl < 16) ? (((n0b + gi * 16 + sl) << 8) | sl) : 0x80;
    }
    if (threadIdx.x < 16) cur[threadIdx.x] = 16;     // self-edges pre-seeded
    __syncthreads();
    for (int i = threadIdx.x; i < n; i += 256) {
        int e = ep[i];
        int g = (e >> 4) & 15;
        int r = atomicAdd(&cur[g], 1);
        if (r < CAPG) image[g * GSTRIDE + r] = e & ~0xF0;   // strip group bits
    }
    __syncthreads();
    if (threadIdx.x < nG) {
        int c = cur[threadIdx.x];
        gcnt[b * 16 + threadIdx.x] = (c > CAPG) ? CAPG : c;
    }
    for (int i = threadIdx.x; i < nG * GSTRIDE; i += 256)
        esd[(size_t)(b * 16) * GSTRIDE + i] = image[i];
}

// ---------------------------------------------------------------------------
// Fused GIN layer, fp8 end-to-end, barrier-free private-wave pipeline
// (identical to the passing R16/R17 kernel).
// ---------------------------------------------------------------------------
__global__ __launch_bounds__(256) void gin_layer(const unsigned char* __restrict__ hf8,
                                                 const int* __restrict__ gcnt,
                                                 const int* __restrict__ esd,
                                                 const short* __restrict__ Wl,
                                                 const float* __restrict__ b1,
                                                 const float* __restrict__ b2,
                                                 const float* __restrict__ eps, int l,
                                                 float* __restrict__ outf,
                                                 unsigned char* __restrict__ outf8,
                                                 int last) {
    __shared__ union {
        unsigned char stg[2][4096];                   // 2 x 4KB fp8 staging
        struct { short zl[2048]; short hl[2048]; } t; // MLP tiles (overlay)
    } sm;
    __shared__ int ilist[MAXCH * 32];                 // 1.5 KB
    __shared__ __align__(8) unsigned char dmask[MAXCH * 32];

    const int lane = threadIdx.x & 63;
    const int wid  = threadIdx.x >> 6;
    const int g    = blockIdx.x;
    const int n0   = g * 16;
    const int m    = lane & 15;          // A-row (node) / C-col
    const int kh   = lane >> 4;          // k-quarter

    const int lo  = g * GSTRIDE;
    int cnt = gcnt[g]; if (cnt > CAPG) cnt = CAPG;
    const int nch = (cnt + 31) >> 5;                 // 1..12 (>=16 self edges)

    // staging-lane geometry (proven in R14)
    const int eL   = ((lane >> 3) & 3) * 8 + (lane & 7);  // edge within chunk
    const int tcol = (wid * 2 + (lane >> 5)) * 16;        // col byte offset

    const uint32_t stg_base =
        (uint32_t)(uintptr_t)(__attribute__((address_space(3))) unsigned char*)&sm.stg[0][0];

    f32x4 acc[2];
    acc[0] = (f32x4)(0.0f); acc[1] = (f32x4)(0.0f);

    const int* ep = esd + lo;

    // ---- prologue: cooperative ilist + dmask build (natural order) ----
    for (int i = threadIdx.x; i < MAXCH * 32; i += 256) {
        int v = ep[i];
        ilist[i] = v;
        dmask[i] = (unsigned char)(v & 0xFF);
    }
    __syncthreads();    // also drains the coop global loads

#define STAGE(c, buf) do { \
        int _i = ilist[(c) * 32 + eL]; \
        __builtin_amdgcn_global_load_lds( \
            (const __attribute__((address_space(1))) void*)(hf8 + (((uint32_t)(_i & ~0xFF)) >> 1) + tcol), \
            (__attribute__((address_space(3))) void*)(&sm.stg[(buf)][wid * 1024]), 16, 0, 0); \
    } while (0)

    if (nch > 0) STAGE(0, 0);
    if (nch > 1) STAGE(1, 1);

    // ---- barrier-free chunk loop (per-wave private pipeline, depth-2) ----
#pragma unroll
    for (int c = 0; c < MAXCH; ++c) {
        if (c >= nch) break;
        if (c + 1 < nch) asm volatile("s_waitcnt vmcnt(1)" ::: "memory");
        else             asm volatile("s_waitcnt vmcnt(0)" ::: "memory");
        __builtin_amdgcn_sched_barrier(0);

        // one tr_b8 per col-tile: full K=32 fp8 B-fragment each
        uint32_t breg = stg_base + (uint32_t)((c & 1) * 4096 + wid * 1024) + lane * 8;
        uint64_t tb0, tb1;
        asm volatile("ds_read_b64_tr_b8 %0, %1"            : "=v"(tb0) : "v"(breg));
        asm volatile("ds_read_b64_tr_b8 %0, %1 offset:512" : "=v"(tb1) : "v"(breg));
        uint2 dm = *(const uint2*)&dmask[c * 32 + kh * 8];
        asm volatile("s_waitcnt lgkmcnt(0)" ::: "memory");
        __builtin_amdgcn_sched_barrier(0);

        // reuse buf[c&1] for chunk c+2 (our own tr reads just retired)
        if (c + 2 < nch) STAGE(c + 2, c & 1);

        // fp8 A-mask via exact per-byte zero-detect: byte k = (dst_k==m)?1.0:0
        uint32_t ms = (uint32_t)m * 0x01010101u;
        uint32_t x0 = dm.x ^ ms, x1 = dm.y ^ ms;
        uint32_t z0 = ~(((x0 & 0x7F7F7F7Fu) + 0x7F7F7F7Fu) | x0) & 0x80808080u;
        uint32_t z1 = ~(((x1 & 0x7F7F7F7Fu) + 0x7F7F7F7Fu) | x1) & 0x80808080u;
        uint32_t alo = (z0 >> 7) * 0x38u;
        uint32_t ahi = (z1 >> 7) * 0x38u;
        long amask = (long)(((uint64_t)ahi << 32) | (uint64_t)alo);

        acc[0] = __builtin_amdgcn_mfma_f32_16x16x32_fp8_fp8(amask, (long)tb0, acc[0], 0, 0, 0);
        acc[1] = __builtin_amdgcn_mfma_f32_16x16x32_fp8_fp8(amask, (long)tb1, acc[1], 0, 0, 0);
    }

    // ---- eps fallback: acc += eps * h[self] (uniform branch; eps=0 here) ----
    {
        const float epsl = eps[l];
        if (epsl != 0.0f) {
#pragma unroll
            for (int t = 0; t < 2; ++t) {
                int col = (wid * 2 + t) * 16 + m;
#pragma unroll
                for (int r = 0; r < 4; ++r) {
                    int row = n0 + kh * 4 + r;
                    acc[t][r] += epsl * fp8_to_f32(hf8[(size_t)row * D + col]);
                }
            }
        }
    }

    __syncthreads();   // drains everything; safe to overlay zl/hl on stg

    // ---- z (C layout) -> zl LDS, granule-swizzled for MLP A-frags ----
#pragma unroll
    for (int t = 0; t < 2; ++t) {
        int col = (wid * 2 + t) * 16 + m;
        int gi = col >> 3, ci = col & 7;
#pragma unroll
        for (int r = 0; r < 4; ++r) {
            int row = kh * 4 + r;
            sm.t.zl[row * 128 + ((gi ^ (row & 7)) << 3) + ci] = f2bf(acc[t][r]);
        }
    }
    __syncthreads();

    // ---- MLP stage 1: hid = relu(z @ W1 + b1) ----
    f32x4 acc1[2];
    acc1[0] = (f32x4)(0.0f); acc1[1] = (f32x4)(0.0f);
#pragma unroll
    for (int ks = 0; ks < 4; ++ks) {
        int gidx = ks * 4 + kh;
        bf16x8 af = *(const bf16x8*)&sm.t.zl[m * 128 + ((gidx ^ (m & 7)) * 8)];
#pragma unroll
        for (int t = 0; t < 2; ++t) {
            int nt = wid * 2 + t;
            bf16x8 bf = *(const bf16x8*)(Wl + ((size_t)(ks * 8 + nt) * 64 + lane) * 8);
            acc1[t] = __builtin_amdgcn_mfma_f32_16x16x32_bf16(af, bf, acc1[t], 0, 0, 0);
        }
    }
#pragma unroll
    for (int t = 0; t < 2; ++t) {
        int col = (wid * 2 + t) * 16 + m;
        float bias = b1[col];
#pragma unroll
        for (int r = 0; r < 4; ++r) {
            int hrow = kh * 4 + r;
            float v = fmaxf(acc1[t][r] + bias, 0.0f);
            sm.t.hl[hrow * 128 + (col ^ ((hrow & 7) << 3))] = f2bf(v);
        }
    }
    __syncthreads();

    // ---- MLP stage 2: out = hid @ W2 + b2 ----
    f32x4 acc2[2];
    acc2[0] = (f32x4)(0.0f); acc2[1] = (f32x4)(0.0f);
    const short* W2p = Wl + 4 * 8 * 64 * 8;
#pragma unroll
    for (int ks = 0; ks < 4; ++ks) {
        int c0 = ks * 32 + kh * 8;
        bf16x8 af = *(const bf16x8*)&sm.t.hl[m * 128 + (c0 ^ ((m & 7) << 3))];
#pragma unroll
        for (int t = 0; t < 2; ++t) {
            int nt = wid * 2 + t;
            bf16x8 bf = *(const bf16x8*)(W2p + ((size_t)(ks * 8 + nt) * 64 + lane) * 8);
            acc2[t] = __builtin_amdgcn_mfma_f32_16x16x32_bf16(af, bf, acc2[t], 0, 0, 0);
        }
    }
#pragma unroll
    for (int t = 0; t < 2; ++t) {
        int col = (wid * 2 + t) * 16 + m;
        float bias = b2[col];
#pragma unroll
        for (int r = 0; r < 4; ++r) {
            int orow = n0 + kh * 4 + r;        // exact grid, always < N_NODES
            float v = acc2[t][r] + bias;
            if (last) outf[(size_t)orow * D + col] = v;
            else      outf8[(size_t)orow * D + col] = f2fp8(v);
        }
    }
#undef STAGE
}

extern "C" void kernel_launch(void* const* d_in, const int* in_sizes, int n_in,
                              void* d_out, int out_size, void* d_ws, size_t ws_size,
                              hipStream_t stream) {
    const float* h   = (const float*)d_in[0];
    const int*   src = (const int*)d_in[1];
    const int*   dst = (const int*)d_in[2];
    const float* W1  = (const float*)d_in[3];
    const float* b1  = (const float*)d_in[4];
    const float* W2  = (const float*)d_in[5];
    const float* b2  = (const float*)d_in[6];
    const float* eps = (const float*)d_in[7];
    float* out = (float*)d_out;

    char* ws = (char*)d_ws;
    const size_t MB = 1024 * 1024;
    unsigned char* hf8A = (unsigned char*)ws;             // 6.4 MB
    unsigned char* hf8B = (unsigned char*)(ws + 7 * MB);  // 6.4 MB
    short* Wswz = (short*)(ws + 14 * MB);                 // 196 KB
    int*   gcnt = (int*)(ws + 14 * MB + 512 * 1024);      // 12.5 KB
    int*   bcur = (int*)(ws + 14 * MB + 768 * 1024);      // 0.8 KB
    int*   esd  = (int*)(ws + 15 * MB);                   // 4.8 MB
    int*   epack= (int*)(ws + 20 * MB);                   // 3.6 MB

    const int prep_blocks = (NW_PREP + NH_PREP + 255) / 256;   // 3174
    prep<<<prep_blocks, 256, 0, stream>>>(W1, W2, Wswz, h, hf8A, bcur);
    packA<<<PA_BLOCKS, 256, 0, stream>>>(src, dst, bcur, epack);
    segB<<<NBKT2, 256, 0, stream>>>(epack, bcur, esd, gcnt);

    const unsigned char* f8in[3] = {hf8A, hf8B, hf8A};
    unsigned char* houtf8[3] = {hf8B, hf8A, nullptr};

    for (int l = 0; l < NLAYER; ++l) {
        gin_layer<<<NGROUP, 256, 0, stream>>>(f8in[l], gcnt, esd,
                                              Wswz + (size_t)l * 2 * 16384,
                                              b1 + (size_t)l * D, b2 + (size_t)l * D,
                                              eps, l, out, houtf8[l],
                                              l == NLAYER - 1 ? 1 : 0);
    }
}